// Round 3
// baseline (197.387 us; speedup 1.0000x reference)
//
#include <hip/hip_runtime.h>
#include <hip/hip_bf16.h>

// Problem constants
#define BATCH  128
#define HWN    196          // (224/16)^2 patches per sample
#define HIDN   768
#define KN     768          // 3*16*16
#define IMGSZ  224
#define IMG2   (224*224)
#define MTOT   (BATCH*HWN)  // 25088 output rows

// GEMM tiling (m97 structure + prefetch dbuf)
#define BM 128
#define BN 128
#define BK 32

typedef __attribute__((ext_vector_type(8))) short bf16x8;
typedef __attribute__((ext_vector_type(4))) float floatx4;

#define GP(p) ((const __attribute__((address_space(1))) void*)(p))
#define SP(p) ((__attribute__((address_space(3))) void*)(p))

static __device__ __forceinline__ short f2bf(float f) {
    __hip_bfloat16 h = __float2bfloat16(f);   // RNE
    return __builtin_bit_cast(short, h);
}

static __device__ __forceinline__ bf16x8 cvt8(const float* __restrict__ src) {
    float4 f0 = *(const float4*)(src);
    float4 f1 = *(const float4*)(src + 4);
    bf16x8 v;
    v[0]=f2bf(f0.x); v[1]=f2bf(f0.y); v[2]=f2bf(f0.z); v[3]=f2bf(f0.w);
    v[4]=f2bf(f1.x); v[5]=f2bf(f1.y); v[6]=f2bf(f1.z); v[7]=f2bf(f1.w);
    return v;
}

// ---------------------------------------------------------------------------
// prep_A: gather + convert. A[gr, k] = bf16(x[b, c, perm-patch pixel]).
// ---------------------------------------------------------------------------
__global__ __launch_bounds__(256)
void prep_A(const float* __restrict__ x, const int* __restrict__ perm,
            unsigned short* __restrict__ A)
{
    const int idx = blockIdx.x * 256 + threadIdx.x;   // < 25088*48
    const int gr  = idx / 48;
    const int seg = idx - gr * 48;                    // 0..47
    const int b   = gr / HWN;
    const int p   = perm[gr];
    const int py  = p / 14, px = p - py * 14;
    const int c   = seg >> 4;                         // 0..2
    const int iy  = seg & 15;                         // 0..15

    const float* src = x + (size_t)b * 3 * IMG2 + (size_t)c * IMG2
                         + (size_t)(py * 16 + iy) * IMGSZ + px * 16;
    bf16x8 v0 = cvt8(src);
    bf16x8 v1 = cvt8(src + 8);
    unsigned short* dst = A + (size_t)gr * KN + seg * 16;
    *(bf16x8*)(dst)     = v0;
    *(bf16x8*)(dst + 8) = v1;
}

// ---------------------------------------------------------------------------
// prep_W: fp32 -> bf16, 768*768 elems, 8 per thread.
// ---------------------------------------------------------------------------
__global__ __launch_bounds__(256)
void prep_W(const float* __restrict__ W, unsigned short* __restrict__ Wb)
{
    const int idx = blockIdx.x * 256 + threadIdx.x;   // < 73728
    const float* src = W + (size_t)idx * 8;
    *(bf16x8*)(Wb + (size_t)idx * 8) = cvt8(src);
}

// ---------------------------------------------------------------------------
// gemm: C[r,n] = sum_k A[r,k]*Wb[n,k] + bias[n]
// - double-buffered LDS, prefetch issued after barrier / before MFMA
// - SWAPPED mfma operands: D is transposed -> lane&15 = out row,
//   quad*4+reg = 4 consecutive out cols -> float4 epilogue stores.
// ---------------------------------------------------------------------------
__global__ __launch_bounds__(256, 4)
void gemm(const unsigned short* __restrict__ A, const unsigned short* __restrict__ Wb,
          const float* __restrict__ bias, float* __restrict__ out)
{
    __shared__ __align__(16) unsigned short As[2][BM * BK];  // 2 x 8 KB
    __shared__ __align__(16) unsigned short Bs[2][BN * BK];  // 2 x 8 KB

    const int tid = threadIdx.x;
    const int bn  = blockIdx.x;   // 0..5   (fast axis: consecutive blocks share A-tile)
    const int bm  = blockIdx.y;   // 0..195

    // staging map: thread t loads 16 B = 8 bf16 of row (t>>2), k-seg (t&3).
    const int srow = tid >> 2;
    const int sseg = tid & 3;
    const unsigned short* ga = A  + (size_t)(bm * BM + srow) * KN + sseg * 8;
    const unsigned short* gb = Wb + (size_t)(bn * BN + srow) * KN + sseg * 8;

    // wave/fragment coords
    const int lane = tid & 63;
    const int wave = tid >> 6;
    const int wm = (wave >> 1) * 64;
    const int wn = (wave & 1) * 64;
    const int lr = lane & 15;
    const int lq = lane >> 4;

    floatx4 acc[4][4] = {};

    auto issue = [&](int k0, int b) {
        __builtin_amdgcn_global_load_lds(GP(ga + k0),           SP(&As[b][tid * 8]),        16, 0, 0);
        __builtin_amdgcn_global_load_lds(GP(ga + 64 * KN + k0), SP(&As[b][2048 + tid * 8]), 16, 0, 0);
        __builtin_amdgcn_global_load_lds(GP(gb + k0),           SP(&Bs[b][tid * 8]),        16, 0, 0);
        __builtin_amdgcn_global_load_lds(GP(gb + 64 * KN + k0), SP(&Bs[b][2048 + tid * 8]), 16, 0, 0);
    };
    auto compute = [&](int b) {
        bf16x8 bfrag[4];
        #pragma unroll
        for (int j = 0; j < 4; ++j)
            bfrag[j] = *(const bf16x8*)&Bs[b][(wn + j * 16 + lr) * BK + lq * 8];
        #pragma unroll
        for (int i = 0; i < 4; ++i) {
            bf16x8 afrag = *(const bf16x8*)&As[b][(wm + i * 16 + lr) * BK + lq * 8];
            #pragma unroll
            for (int j = 0; j < 4; ++j)   // swapped operands -> transposed D
                acc[i][j] = __builtin_amdgcn_mfma_f32_16x16x32_bf16(
                                bfrag[j], afrag, acc[i][j], 0, 0, 0);
        }
    };

    issue(0, 0);
    for (int k0 = 0; k0 < KN; k0 += 2 * BK) {
        __syncthreads();                       // buf0 ready; buf1 reads done
        if (k0 + BK < KN) issue(k0 + BK, 1);   // prefetch overlaps compute(0)
        compute(0);
        __syncthreads();                       // buf1 ready; buf0 reads done
        if (k0 + 2 * BK < KN) issue(k0 + 2 * BK, 0);
        compute(1);
    }

    // epilogue: transposed C/D -> row = lr, 4 consecutive cols = lq*4 + reg
    #pragma unroll
    for (int j = 0; j < 4; ++j) {
        const int gc0 = bn * BN + wn + j * 16 + lq * 4;
        const float4 bv = *(const float4*)&bias[gc0];
        #pragma unroll
        for (int i = 0; i < 4; ++i) {
            const int grow = bm * BM + wm + i * 16 + lr;
            float4 v;
            v.x = acc[i][j][0] + bv.x;
            v.y = acc[i][j][1] + bv.y;
            v.z = acc[i][j][2] + bv.z;
            v.w = acc[i][j][3] + bv.w;
            *(float4*)(out + (size_t)grow * HIDN + gc0) = v;
        }
    }
}

extern "C" void kernel_launch(void* const* d_in, const int* in_sizes, int n_in,
                              void* d_out, int out_size, void* d_ws, size_t ws_size,
                              hipStream_t stream) {
    const float* x    = (const float*)d_in[0];
    const float* W    = (const float*)d_in[1];
    const float* bias = (const float*)d_in[2];
    const int*   perm = (const int*)d_in[3];
    float* out = (float*)d_out;

    // workspace layout: A bf16 [25088*768] (38.5 MB), Wb bf16 [768*768] (1.2 MB)
    unsigned short* A  = (unsigned short*)d_ws;
    unsigned short* Wb = A + (size_t)MTOT * KN;

    prep_A<<<dim3(MTOT * 48 / 256), dim3(256), 0, stream>>>(x, perm, A);
    prep_W<<<dim3(KN * HIDN / 8 / 256), dim3(256), 0, stream>>>(W, Wb);
    gemm<<<dim3(HIDN / BN, MTOT / BM), dim3(256), 0, stream>>>(A, Wb, bias, out);
}

// Round 4
// 192.350 us; speedup vs baseline: 1.0262x; 1.0262x over previous
//
#include <hip/hip_runtime.h>
#include <hip/hip_bf16.h>

// Problem constants
#define BATCH  128
#define HWN    196          // (224/16)^2 patches per sample
#define HIDN   768
#define KN     768          // 3*16*16
#define IMGSZ  224
#define IMG2   (224*224)
#define MTOT   (BATCH*HWN)  // 25088 output rows

// GEMM tiling
#define BM 128
#define BN 128
#define BK 32

typedef __attribute__((ext_vector_type(8))) short bf16x8;
typedef __attribute__((ext_vector_type(4))) float floatx4;

#define GP(p) ((const __attribute__((address_space(1))) void*)(p))
#define SP(p) ((__attribute__((address_space(3))) void*)(p))

static __device__ __forceinline__ short f2bf(float f) {
    __hip_bfloat16 h = __float2bfloat16(f);   // RNE
    return __builtin_bit_cast(short, h);
}

static __device__ __forceinline__ bf16x8 cvt8(const float* __restrict__ src) {
    float4 f0 = *(const float4*)(src);
    float4 f1 = *(const float4*)(src + 4);
    bf16x8 v;
    v[0]=f2bf(f0.x); v[1]=f2bf(f0.y); v[2]=f2bf(f0.z); v[3]=f2bf(f0.w);
    v[4]=f2bf(f1.x); v[5]=f2bf(f1.y); v[6]=f2bf(f1.z); v[7]=f2bf(f1.w);
    return v;
}

// ---------------------------------------------------------------------------
// prep_A: gather + convert. A[gr, k] = bf16(x[b, c, perm-patch pixel]).
// ---------------------------------------------------------------------------
__global__ __launch_bounds__(256)
void prep_A(const float* __restrict__ x, const int* __restrict__ perm,
            unsigned short* __restrict__ A)
{
    const int idx = blockIdx.x * 256 + threadIdx.x;   // < 25088*48
    const int gr  = idx / 48;
    const int seg = idx - gr * 48;                    // 0..47
    const int b   = gr / HWN;
    const int p   = perm[gr];
    const int py  = p / 14, px = p - py * 14;
    const int c   = seg >> 4;                         // 0..2
    const int iy  = seg & 15;                         // 0..15

    const float* src = x + (size_t)b * 3 * IMG2 + (size_t)c * IMG2
                         + (size_t)(py * 16 + iy) * IMGSZ + px * 16;
    bf16x8 v0 = cvt8(src);
    bf16x8 v1 = cvt8(src + 8);
    unsigned short* dst = A + (size_t)gr * KN + seg * 16;
    *(bf16x8*)(dst)     = v0;
    *(bf16x8*)(dst + 8) = v1;
}

// ---------------------------------------------------------------------------
// prep_W: fp32 -> bf16, 768*768 elems, 8 per thread.
// ---------------------------------------------------------------------------
__global__ __launch_bounds__(256)
void prep_W(const float* __restrict__ W, unsigned short* __restrict__ Wb)
{
    const int idx = blockIdx.x * 256 + threadIdx.x;   // < 73728
    const float* src = W + (size_t)idx * 8;
    *(bf16x8*)(Wb + (size_t)idx * 8) = cvt8(src);
}

// ---------------------------------------------------------------------------
// gemm: C[r,n] = sum_k A[r,k]*Wb[n,k] + bias[n]
// 1D grid, XCD-partitioned tile mapping (RR linear-id -> XCD assumption):
//   xcd = L&7 keeps all 6 bn-tiles of one bm-group on ONE XCD, bn-fastest,
//   so each A-tile is L2-filled once instead of up to 6 times.
// Double-buffered LDS + async global_load_lds; transposed-D float4 epilogue.
// ---------------------------------------------------------------------------
__global__ __launch_bounds__(256, 5)
void gemm(const unsigned short* __restrict__ A, const unsigned short* __restrict__ Wb,
          const float* __restrict__ bias, float* __restrict__ out)
{
    __shared__ __align__(16) unsigned short As[2][BM * BK];  // 2 x 8 KB
    __shared__ __align__(16) unsigned short Bs[2][BN * BK];  // 2 x 8 KB

    const int tid = threadIdx.x;

    // ---- XCD-partitioned tile decode: 1176 tiles, 8 groups of bm
    // groups 0..3: 25 bm-tiles (150 tiles), groups 4..7: 24 (144 tiles).
    // XCD k has 147 slots; low groups' overflow (3 tiles) goes to xcd k+4.
    const int L   = blockIdx.x;       // 0..1175
    const int xcd = L & 7;
    const int s   = L >> 3;           // 0..146
    int grp, t;
    if (xcd < 4)        { grp = xcd;     t = s; }
    else if (s < 144)   { grp = xcd;     t = s; }
    else                { grp = xcd - 4; t = 147 + (s - 144); }
    const int bm0 = (grp < 4) ? grp * 25 : 100 + (grp - 4) * 24;
    const int bm  = bm0 + t / 6;      // 0..195
    const int bn  = t % 6;            // bn-fastest: 6 same-A tiles consecutive

    // staging map: thread t loads 16 B = 8 bf16 of row (t>>2), k-seg (t&3).
    const int srow = tid >> 2;
    const int sseg = tid & 3;
    const unsigned short* ga = A  + (size_t)(bm * BM + srow) * KN + sseg * 8;
    const unsigned short* gb = Wb + (size_t)(bn * BN + srow) * KN + sseg * 8;

    // wave/fragment coords
    const int lane = tid & 63;
    const int wave = tid >> 6;
    const int wm = (wave >> 1) * 64;
    const int wn = (wave & 1) * 64;
    const int lr = lane & 15;
    const int lq = lane >> 4;

    floatx4 acc[4][4] = {};

    auto issue = [&](int k0, int b) {
        __builtin_amdgcn_global_load_lds(GP(ga + k0),           SP(&As[b][tid * 8]),        16, 0, 0);
        __builtin_amdgcn_global_load_lds(GP(ga + 64 * KN + k0), SP(&As[b][2048 + tid * 8]), 16, 0, 0);
        __builtin_amdgcn_global_load_lds(GP(gb + k0),           SP(&Bs[b][tid * 8]),        16, 0, 0);
        __builtin_amdgcn_global_load_lds(GP(gb + 64 * KN + k0), SP(&Bs[b][2048 + tid * 8]), 16, 0, 0);
    };
    auto compute = [&](int b) {
        bf16x8 bfrag[4];
        #pragma unroll
        for (int j = 0; j < 4; ++j)
            bfrag[j] = *(const bf16x8*)&Bs[b][(wn + j * 16 + lr) * BK + lq * 8];
        #pragma unroll
        for (int i = 0; i < 4; ++i) {
            bf16x8 afrag = *(const bf16x8*)&As[b][(wm + i * 16 + lr) * BK + lq * 8];
            #pragma unroll
            for (int j = 0; j < 4; ++j)   // swapped operands -> transposed D
                acc[i][j] = __builtin_amdgcn_mfma_f32_16x16x32_bf16(
                                bfrag[j], afrag, acc[i][j], 0, 0, 0);
        }
    };

    issue(0, 0);
    for (int k0 = 0; k0 < KN; k0 += 2 * BK) {
        __syncthreads();                       // buf0 ready; buf1 reads done
        if (k0 + BK < KN) issue(k0 + BK, 1);   // prefetch overlaps compute(0)
        compute(0);
        __syncthreads();                       // buf1 ready; buf0 reads done
        if (k0 + 2 * BK < KN) issue(k0 + 2 * BK, 0);
        compute(1);
    }

    // epilogue: transposed C/D -> row = lr, 4 consecutive cols = lq*4 + reg
    #pragma unroll
    for (int j = 0; j < 4; ++j) {
        const int gc0 = bn * BN + wn + j * 16 + lq * 4;
        const float4 bv = *(const float4*)&bias[gc0];
        #pragma unroll
        for (int i = 0; i < 4; ++i) {
            const int grow = bm * BM + wm + i * 16 + lr;
            float4 v;
            v.x = acc[i][j][0] + bv.x;
            v.y = acc[i][j][1] + bv.y;
            v.z = acc[i][j][2] + bv.z;
            v.w = acc[i][j][3] + bv.w;
            *(float4*)(out + (size_t)grow * HIDN + gc0) = v;
        }
    }
}

extern "C" void kernel_launch(void* const* d_in, const int* in_sizes, int n_in,
                              void* d_out, int out_size, void* d_ws, size_t ws_size,
                              hipStream_t stream) {
    const float* x    = (const float*)d_in[0];
    const float* W    = (const float*)d_in[1];
    const float* bias = (const float*)d_in[2];
    const int*   perm = (const int*)d_in[3];
    float* out = (float*)d_out;

    // workspace layout: A bf16 [25088*768] (38.5 MB), Wb bf16 [768*768] (1.2 MB)
    unsigned short* A  = (unsigned short*)d_ws;
    unsigned short* Wb = A + (size_t)MTOT * KN;

    prep_A<<<dim3(MTOT * 48 / 256), dim3(256), 0, stream>>>(x, perm, A);
    prep_W<<<dim3(KN * HIDN / 8 / 256), dim3(256), 0, stream>>>(W, Wb);
    gemm<<<dim3(1176), dim3(256), 0, stream>>>(A, Wb, bias, out);
}